// Round 13
// baseline (96.596 us; speedup 1.0000x reference)
//
#include <hip/hip_runtime.h>

#define WSZ 2
#define ZNEAR 0.1f
#define ZFAR 100.0f
#define NT 256
#define CHUNK 1536        // round 13: 6 points/thread, all taps in one pipeline group
#define KPT (CHUNK / NT)  // 6
#define GRP 6             // tap-pipeline group size (1.5x MLP vs round-11)
#define CELLSZ 6144       // K2 LDS z-buffer ints (24 KB)
#define THIST 256         // max bins (row-bands) per batch
#define CSTRIDE 16        // 64B padding for global per-bin counters

// Tile geometry from runtime h,w — identical in K1/K2.
// rpt = SMALLEST even rows/tile with tpb <= THIST (max K2 parallelism).
__device__ __forceinline__ void derive_geom(int h, int w, int n,
                                            int& H2, int& W2, int& rpt,
                                            int& cpt, int& tpb, bool& ok) {
    H2 = h * WSZ; W2 = w * WSZ;
    rpt = (H2 + THIST - 1) / THIST;
    rpt = (rpt + 1) & ~1;                          // round up to even
    if (rpt < 2) rpt = 2;
    cpt = rpt * W2;                                // cells per tile
    tpb = (H2 + rpt - 1) / rpt;                    // tiles (bins) per batch
    ok = (cpt <= CELLSZ) && (tpb <= THIST) && (n <= (1 << 19)) && (cpt <= 8192);
}

// ---------------------------------------------------------------------------
// K1: fused projection + beta bilinear (out_conf) + binning.  (round-11 body,
// only CHUNK/KPT/GRP changed: deeper tap MLP below the register cliff)
// ---------------------------------------------------------------------------
__global__ void __launch_bounds__(NT)
project_bin_kernel(const float* __restrict__ pp,    // [b,7,n]
                   const float* __restrict__ conf,  // [b,n]
                   const float* __restrict__ pose,  // [b,4,4]
                   const float* __restrict__ Kmat,  // [b,3,3]
                   const float* __restrict__ beta,  // [b,1,h,w]
                   const int* __restrict__ d_h,
                   const int* __restrict__ d_w,
                   int* __restrict__ counters,          // [nb_ub*CSTRIDE]
                   unsigned int* __restrict__ records,  // [nb_ub*cap]
                   float* __restrict__ out_conf,        // [b*n]
                   int n, int b, int cap) {
    __shared__ unsigned int staging[CHUNK];
    __shared__ int hist[THIST];
    __shared__ int segstart[THIST];
    __shared__ int cursor[THIST];
    __shared__ int gbase[THIST];
    __shared__ int wsum[NT / 64];
    __shared__ int tot_s;

    const int h = *d_h, w = *d_w;
    int H2, W2, rpt, cpt, tpb; bool geom_ok;
    derive_geom(h, w, n, H2, W2, rpt, cpt, tpb, geom_ok);

    // XCD-affinity remap (batch = blockIdx % b)
    const int b_idx = blockIdx.x % b;
    const int off   = (blockIdx.x / b) * CHUNK;
    const int tid   = threadIdx.x;

    hist[tid] = 0;
    __syncthreads();

    const float* P  = pose + b_idx * 16;
    const float* Kb = Kmat + b_idx * 9;
    const float fxk = Kb[0], cxk = Kb[2], fyk = Kb[4], cyk = Kb[5];
    const float p00 = P[0], p01 = P[1], p02 = P[2],  p03 = P[3];
    const float p10 = P[4], p11 = P[5], p12 = P[6],  p13 = P[7];
    const float p20 = P[8], p21 = P[9], p22 = P[10], p23 = P[11];
    const float* B = beta + (size_t)b_idx * h * w;

    unsigned int words[KPT];
    #pragma unroll
    for (int k = 0; k < KPT; ++k) words[k] = 0xFFFFFFFFu;

    // ---- phase A: pipelined in groups of GRP ----
    #pragma unroll
    for (int g = 0; g < KPT; g += GRP) {
        float xc_[GRP], yc_[GRP], z_[GRP], cf_[GRP], ix_[GRP], iy_[GRP];
        bool act_[GRP], sok_[GRP];

        // A1: batched pp/conf loads + projection for GRP points
        #pragma unroll
        for (int q = 0; q < GRP; ++q) {
            int k = g + q;
            int i = off + k * NT + tid;
            bool act = (i < n);
            act_[q] = act;
            float px = 0.f, py = 0.f, pz = 0.f, pw = 0.f, cf = 0.f;
            if (act) {
                const float* ppb = pp + (size_t)b_idx * 7 * n + i;
                px = __builtin_nontemporal_load(ppb);
                py = __builtin_nontemporal_load(ppb + (size_t)n);
                pz = __builtin_nontemporal_load(ppb + (size_t)2 * n);
                pw = __builtin_nontemporal_load(ppb + (size_t)3 * n);
                cf = conf[(size_t)b_idx * n + i];
            }
            float pc0 = p00 * px + p01 * py + p02 * pz + p03 * pw;
            float pc1 = p10 * px + p11 * py + p12 * pz + p13 * pw;
            float pc2 = p20 * px + p21 * py + p22 * pz + p23 * pw;
            float z = fabsf(pc2);
            float xc = pc0 * fxk / z + cxk;
            float yc = pc1 * fyk / z + cyk;
            // verbatim fp order for sampling coords
            float gx = xc / (float)(w - 1) * 2.0f - 1.0f;
            float gy = -(yc / (float)(h - 1) * 2.0f - 1.0f);
            float ix = (gx + 1.0f) * 0.5f * (float)(w - 1);
            float iy = (gy + 1.0f) * 0.5f * (float)(h - 1);
            xc_[q] = xc; yc_[q] = yc; z_[q] = z; cf_[q] = cf;
            ix_[q] = ix; iy_[q] = iy;
            sok_[q] = act && (ix > -1.0f) && (ix < (float)w)
                          && (iy > -1.0f) && (iy < (float)h);
        }

        // A2: issue all tap loads for the group (ILP across GRP points)
        float t00[GRP], t10[GRP], t01[GRP], t11[GRP];
        #pragma unroll
        for (int q = 0; q < GRP; ++q) {
            t00[q] = t10[q] = t01[q] = t11[q] = 0.0f;
            if (!sok_[q]) continue;
            int x0 = (int)floorf(ix_[q]);
            int y0 = (int)floorf(iy_[q]);
            bool pair = (x0 >= 0) && (x0 + 1 < w) && ((x0 & 1) == 0);
            if (y0 >= 0 && y0 < h) {
                const float* R = B + (size_t)y0 * w;
                if (pair) {
                    float2 p2 = *reinterpret_cast<const float2*>(R + x0);
                    t00[q] = p2.x; t10[q] = p2.y;
                } else {
                    if (x0 >= 0 && x0 < w)         t00[q] = R[x0];
                    if (x0 + 1 >= 0 && x0 + 1 < w) t10[q] = R[x0 + 1];
                }
            }
            if (y0 + 1 >= 0 && y0 + 1 < h) {
                const float* R = B + (size_t)(y0 + 1) * w;
                if (pair) {
                    float2 p2 = *reinterpret_cast<const float2*>(R + x0);
                    t01[q] = p2.x; t11[q] = p2.y;
                } else {
                    if (x0 >= 0 && x0 < w)         t01[q] = R[x0];
                    if (x0 + 1 >= 0 && x0 + 1 < w) t11[q] = R[x0 + 1];
                }
            }
        }

        // A3: combine + out_conf store + validity/bin classify
        #pragma unroll
        for (int q = 0; q < GRP; ++q) {
            int k = g + q;
            int i = off + k * NT + tid;
            if (!act_[q]) continue;
            float cs = 0.0f;
            if (sok_[q]) {
                float x0f = floorf(ix_[q]), y0f = floorf(iy_[q]);
                float wx = ix_[q] - x0f, wy = iy_[q] - y0f;
                cs = t00[q] * (1.0f - wx) * (1.0f - wy)
                   + t10[q] * wx * (1.0f - wy)
                   + t01[q] * (1.0f - wx) * wy
                   + t11[q] * wx * wy;
            }
            __builtin_nontemporal_store(cs, out_conf + (size_t)b_idx * n + i);

            float rx = rintf(xc_[q] * (float)WSZ);  // jnp.round = half-to-even
            float ry = rintf(yc_[q] * (float)WSZ);
            bool valid = (rx >= 0.0f) && (rx < (float)W2) &&
                         (ry >= 0.0f) && (ry < (float)H2) &&
                         (z_[q] >= ZNEAR) && (z_[q] <= ZFAR) && (cf_[q] > 0.0f);
            if (valid && geom_ok) {
                int xs = (int)rx, ys = (int)ry;
                int ty = (int)((unsigned)ys / (unsigned)rpt);
                int cib = (ys - ty * rpt) * W2 + xs;
                words[k] = ((unsigned)ty << 13) | (unsigned)cib;
                atomicAdd(&hist[ty], 1);
            }
        }
    }
    __syncthreads();

    // ---- exclusive scan of hist via wave shuffles ----
    const int lane = tid & 63, wv = tid >> 6;
    int own = hist[tid];
    int v = own;
    #pragma unroll
    for (int s = 1; s < 64; s <<= 1) {
        int u = __shfl_up(v, s, 64);
        if (lane >= s) v += u;
    }
    if (lane == 63) wsum[wv] = v;
    __syncthreads();
    int basew = 0;
    #pragma unroll
    for (int t = 0; t < NT / 64; ++t)
        if (t < wv) basew += wsum[t];
    int incl = basew + v;
    int sstart = incl - own;
    segstart[tid] = sstart;
    cursor[tid] = sstart;
    if (tid == NT - 1) tot_s = incl;
    // one global atomicAdd per active bin to reserve record space
    gbase[tid] = (tid < tpb && own > 0)
               ? atomicAdd(&counters[(b_idx * tpb + tid) * CSTRIDE], own) : 0;
    __syncthreads();

    // ---- phase B: scatter records into LDS staging ----
    #pragma unroll
    for (int k = 0; k < KPT; ++k) {
        unsigned int word = words[k];
        if (word == 0xFFFFFFFFu) continue;
        int ty = (int)(word >> 13);
        unsigned int cib = word & 8191u;
        int i = off + k * NT + tid;
        int slot = atomicAdd(&cursor[ty], 1);               // < CHUNK always
        staging[slot] = (cib << 19) | (unsigned)i;
    }
    __syncthreads();

    // ---- phase C: dense cooperative flush (all 256 lanes active) ----
    const int tot = tot_s;
    for (int j = tid; j < tot; j += NT) {
        // binary search: largest t with segstart[t] <= j
        int lo = 0, hi = THIST - 1;
        while (lo < hi) {
            int mid = (lo + hi + 1) >> 1;
            if (segstart[mid] <= j) lo = mid; else hi = mid - 1;
        }
        int t = lo;
        int gpos = gbase[t] + (j - segstart[t]);
        if (gpos < cap)                                      // drop-guard
            records[(size_t)(b_idx * tpb + t) * cap + gpos] = staging[j];
    }
}

// ---------------------------------------------------------------------------
// K2: per-bin LDS z-buffer replay + 2x2 argmax-by-conf pool + vflip + outputs.
// (verbatim round-11, validated)
// ---------------------------------------------------------------------------
__global__ void __launch_bounds__(NT)
pool_bins_kernel(const float* __restrict__ alpha,   // [b,1,h,w]
                 const float* __restrict__ conf,    // [b,n]
                 const int* __restrict__ counters,
                 const unsigned int* __restrict__ records,
                 const int* __restrict__ d_h,
                 const int* __restrict__ d_w,
                 float* __restrict__ out_match,     // [b,h,w]
                 float* __restrict__ out_midx,      // [b,h,w]
                 int b, int n, int hw, int cap) {
    __shared__ int cells[CELLSZ];
    const int h = *d_h, w = *d_w;
    int H2, W2, rpt, cpt, tpb; bool geom_ok;
    derive_geom(h, w, n, H2, W2, rpt, cpt, tpb, geom_ok);
    if (!geom_ok) return;

    // XCD-affinity remap
    const int b_idx = blockIdx.x % b;
    const int ty    = blockIdx.x / b;
    if (ty >= tpb) return;
    const int bin = b_idx * tpb + ty;

    for (int i = threadIdx.x; i < cpt; i += NT) cells[i] = -1;
    __syncthreads();

    int cnt = counters[bin * CSTRIDE];
    if (cnt > cap) cnt = cap;
    const unsigned int* rec = records + (size_t)bin * cap;
    for (int r = threadIdx.x; r < cnt; r += NT) {
        unsigned int rr = rec[r];
        atomicMax(&cells[rr >> 19], (int)(rr & 0x7FFFFu));   // winner = max idx
    }
    __syncthreads();

    const int row0 = ty * rpt;
    int rmax = H2 - row0; if (rmax > rpt) rmax = rpt;         // even
    const float* A = alpha + (size_t)b_idx * hw;
    const float* C = conf + (size_t)b_idx * n;

    for (int q = 0; q < rmax / 2; ++q) {
        int hr = (row0 >> 1) + q;
        int r_out = h - 1 - hr;                               // vertical flip
        for (int c = threadIdx.x; c < w; c += NT) {
            // alpha gate uniform across the 2x2 window: = alpha[r_out][c]
            float av = A[r_out * w + c];
            float best = 0.0f;
            int besti = -1;
            if (av > 0.0f) {
                #pragma unroll
                for (int a = 0; a < 4; ++a) {
                    int dy = a >> 1, dx = a & 1;
                    int widx = cells[(2 * q + dy) * W2 + 2 * c + dx];
                    if (widx >= 0) {
                        float cv = C[widx];                   // always > 0
                        if (cv > best) { best = cv; besti = widx; }
                    }
                }
            }
            int o = b_idx * hw + r_out * w + c;
            out_match[o] = (best > 0.0f) ? 1.0f : 0.0f;
            out_midx[o]  = (float)besti;
        }
    }
}

extern "C" void kernel_launch(void* const* d_in, const int* in_sizes, int n_in,
                              void* d_out, int out_size, void* d_ws, size_t ws_size,
                              hipStream_t stream) {
    const float* alpha = (const float*)d_in[0];
    const float* beta  = (const float*)d_in[1];
    const float* pp    = (const float*)d_in[2];
    const float* conf  = (const float*)d_in[3];
    const float* pose  = (const float*)d_in[4];
    const float* Kmat  = (const float*)d_in[5];
    const int*   d_h   = (const int*)d_in[6];
    const int*   d_w   = (const int*)d_in[7];

    const int b  = in_sizes[4] / 16;     // pose [b,4,4]
    const int n  = in_sizes[3] / b;      // conf [b,n]
    const int hw = in_sizes[0] / b;      // alpha [b,1,h,w]

    float* out_match = (float*)d_out;
    float* out_midx  = out_match + (size_t)b * hw;
    float* out_conf  = out_midx + (size_t)b * hw;

    // tpb <= THIST always, so b*THIST bounds total bins.
    const int nb_ub = b * THIST;

    // Workspace layout: [counters | records]
    long avail_ints = (long)(ws_size / 4) - (long)nb_ub * CSTRIDE;
    long cap_l = avail_ints / (nb_ub > 0 ? nb_ub : 1);
    int cap = (int)cap_l;
    if (cap > 4096) cap = 4096;
    if (cap < 64) cap = 64;

    int* counters = (int*)d_ws;
    unsigned int* records = (unsigned int*)(counters + (size_t)nb_ub * CSTRIDE);

    // counters init via memset (graph-capturable)
    hipMemsetAsync(counters, 0, (size_t)nb_ub * CSTRIDE * sizeof(int), stream);

    const int bpb = (n + CHUNK - 1) / CHUNK;   // blocks per batch
    project_bin_kernel<<<b * bpb, NT, 0, stream>>>(
        pp, conf, pose, Kmat, beta, d_h, d_w,
        counters, records, out_conf, n, b, cap);

    pool_bins_kernel<<<nb_ub, NT, 0, stream>>>(
        alpha, conf, counters, records, d_h, d_w,
        out_match, out_midx, b, n, hw, cap);
}

// Round 14
// 85.441 us; speedup vs baseline: 1.1306x; 1.1306x over previous
//
#include <hip/hip_runtime.h>

#define WSZ 2
#define ZNEAR 0.1f
#define ZFAR 100.0f
#define NT 256
#define CHUNK 2048        // points per block in K1 (8 per thread) — round-8/11 best
#define KPT (CHUNK / NT)  // 8
#define GRP 4             // tap-pipeline group size — best measured
#define CELLSZ 6144       // K2 LDS z-buffer ints (24 KB)
#define THIST 256         // max bins (row-bands) per batch
#define CSTRIDE 16        // 64B padding for global per-bin counters

// Tile geometry from runtime h,w — identical in K1/K2.
// rpt = SMALLEST even rows/tile with tpb <= THIST (max K2 parallelism).
__device__ __forceinline__ void derive_geom(int h, int w, int n,
                                            int& H2, int& W2, int& rpt,
                                            int& cpt, int& tpb, bool& ok) {
    H2 = h * WSZ; W2 = w * WSZ;
    rpt = (H2 + THIST - 1) / THIST;
    rpt = (rpt + 1) & ~1;                          // round up to even
    if (rpt < 2) rpt = 2;
    cpt = rpt * W2;                                // cells per tile
    tpb = (H2 + rpt - 1) / rpt;                    // tiles (bins) per batch
    ok = (cpt <= CELLSZ) && (tpb <= THIST) && (n <= (1 << 19)) && (cpt <= 8192);
}

// ---------------------------------------------------------------------------
// K1: fused projection + beta bilinear (out_conf) + binning.
// Best measured config: CHUNK=2048, GRP=4, branchy float2 taps, dense flush,
// nontemporal pp/out_conf streams, XCD-affinity batch mapping.
// ---------------------------------------------------------------------------
__global__ void __launch_bounds__(NT)
project_bin_kernel(const float* __restrict__ pp,    // [b,7,n]
                   const float* __restrict__ conf,  // [b,n]
                   const float* __restrict__ pose,  // [b,4,4]
                   const float* __restrict__ Kmat,  // [b,3,3]
                   const float* __restrict__ beta,  // [b,1,h,w]
                   const int* __restrict__ d_h,
                   const int* __restrict__ d_w,
                   int* __restrict__ counters,          // [nb_ub*CSTRIDE]
                   unsigned int* __restrict__ records,  // [nb_ub*cap]
                   float* __restrict__ out_conf,        // [b*n]
                   int n, int b, int cap) {
    __shared__ unsigned int staging[CHUNK];
    __shared__ int hist[THIST];
    __shared__ int segstart[THIST];
    __shared__ int cursor[THIST];
    __shared__ int gbase[THIST];
    __shared__ int wsum[NT / 64];
    __shared__ int tot_s;

    const int h = *d_h, w = *d_w;
    int H2, W2, rpt, cpt, tpb; bool geom_ok;
    derive_geom(h, w, n, H2, W2, rpt, cpt, tpb, geom_ok);

    // XCD-affinity remap (batch = blockIdx % b)
    const int b_idx = blockIdx.x % b;
    const int off   = (blockIdx.x / b) * CHUNK;
    const int tid   = threadIdx.x;

    hist[tid] = 0;
    __syncthreads();

    const float* P  = pose + b_idx * 16;
    const float* Kb = Kmat + b_idx * 9;
    const float fxk = Kb[0], cxk = Kb[2], fyk = Kb[4], cyk = Kb[5];
    const float p00 = P[0], p01 = P[1], p02 = P[2],  p03 = P[3];
    const float p10 = P[4], p11 = P[5], p12 = P[6],  p13 = P[7];
    const float p20 = P[8], p21 = P[9], p22 = P[10], p23 = P[11];
    const float* B = beta + (size_t)b_idx * h * w;

    unsigned int words[KPT];
    #pragma unroll
    for (int k = 0; k < KPT; ++k) words[k] = 0xFFFFFFFFu;

    // ---- phase A: pipelined in groups of GRP ----
    #pragma unroll
    for (int g = 0; g < KPT; g += GRP) {
        float xc_[GRP], yc_[GRP], z_[GRP], cf_[GRP], ix_[GRP], iy_[GRP];
        bool act_[GRP], sok_[GRP];

        // A1: batched pp/conf loads + projection for GRP points
        #pragma unroll
        for (int q = 0; q < GRP; ++q) {
            int k = g + q;
            int i = off + k * NT + tid;
            bool act = (i < n);
            act_[q] = act;
            float px = 0.f, py = 0.f, pz = 0.f, pw = 0.f, cf = 0.f;
            if (act) {
                const float* ppb = pp + (size_t)b_idx * 7 * n + i;
                px = __builtin_nontemporal_load(ppb);
                py = __builtin_nontemporal_load(ppb + (size_t)n);
                pz = __builtin_nontemporal_load(ppb + (size_t)2 * n);
                pw = __builtin_nontemporal_load(ppb + (size_t)3 * n);
                cf = conf[(size_t)b_idx * n + i];
            }
            float pc0 = p00 * px + p01 * py + p02 * pz + p03 * pw;
            float pc1 = p10 * px + p11 * py + p12 * pz + p13 * pw;
            float pc2 = p20 * px + p21 * py + p22 * pz + p23 * pw;
            float z = fabsf(pc2);
            float xc = pc0 * fxk / z + cxk;
            float yc = pc1 * fyk / z + cyk;
            // verbatim fp order for sampling coords
            float gx = xc / (float)(w - 1) * 2.0f - 1.0f;
            float gy = -(yc / (float)(h - 1) * 2.0f - 1.0f);
            float ix = (gx + 1.0f) * 0.5f * (float)(w - 1);
            float iy = (gy + 1.0f) * 0.5f * (float)(h - 1);
            xc_[q] = xc; yc_[q] = yc; z_[q] = z; cf_[q] = cf;
            ix_[q] = ix; iy_[q] = iy;
            sok_[q] = act && (ix > -1.0f) && (ix < (float)w)
                          && (iy > -1.0f) && (iy < (float)h);
        }

        // A2: issue all tap loads for the group (ILP across GRP points)
        float t00[GRP], t10[GRP], t01[GRP], t11[GRP];
        #pragma unroll
        for (int q = 0; q < GRP; ++q) {
            t00[q] = t10[q] = t01[q] = t11[q] = 0.0f;
            if (!sok_[q]) continue;
            int x0 = (int)floorf(ix_[q]);
            int y0 = (int)floorf(iy_[q]);
            bool pair = (x0 >= 0) && (x0 + 1 < w) && ((x0 & 1) == 0);
            if (y0 >= 0 && y0 < h) {
                const float* R = B + (size_t)y0 * w;
                if (pair) {
                    float2 p2 = *reinterpret_cast<const float2*>(R + x0);
                    t00[q] = p2.x; t10[q] = p2.y;
                } else {
                    if (x0 >= 0 && x0 < w)         t00[q] = R[x0];
                    if (x0 + 1 >= 0 && x0 + 1 < w) t10[q] = R[x0 + 1];
                }
            }
            if (y0 + 1 >= 0 && y0 + 1 < h) {
                const float* R = B + (size_t)(y0 + 1) * w;
                if (pair) {
                    float2 p2 = *reinterpret_cast<const float2*>(R + x0);
                    t01[q] = p2.x; t11[q] = p2.y;
                } else {
                    if (x0 >= 0 && x0 < w)         t01[q] = R[x0];
                    if (x0 + 1 >= 0 && x0 + 1 < w) t11[q] = R[x0 + 1];
                }
            }
        }

        // A3: combine + out_conf store + validity/bin classify
        #pragma unroll
        for (int q = 0; q < GRP; ++q) {
            int k = g + q;
            int i = off + k * NT + tid;
            if (!act_[q]) continue;
            float cs = 0.0f;
            if (sok_[q]) {
                float x0f = floorf(ix_[q]), y0f = floorf(iy_[q]);
                float wx = ix_[q] - x0f, wy = iy_[q] - y0f;
                cs = t00[q] * (1.0f - wx) * (1.0f - wy)
                   + t10[q] * wx * (1.0f - wy)
                   + t01[q] * (1.0f - wx) * wy
                   + t11[q] * wx * wy;
            }
            __builtin_nontemporal_store(cs, out_conf + (size_t)b_idx * n + i);

            float rx = rintf(xc_[q] * (float)WSZ);  // jnp.round = half-to-even
            float ry = rintf(yc_[q] * (float)WSZ);
            bool valid = (rx >= 0.0f) && (rx < (float)W2) &&
                         (ry >= 0.0f) && (ry < (float)H2) &&
                         (z_[q] >= ZNEAR) && (z_[q] <= ZFAR) && (cf_[q] > 0.0f);
            if (valid && geom_ok) {
                int xs = (int)rx, ys = (int)ry;
                int ty = (int)((unsigned)ys / (unsigned)rpt);
                int cib = (ys - ty * rpt) * W2 + xs;
                words[k] = ((unsigned)ty << 13) | (unsigned)cib;
                atomicAdd(&hist[ty], 1);
            }
        }
    }
    __syncthreads();

    // ---- exclusive scan of hist via wave shuffles ----
    const int lane = tid & 63, wv = tid >> 6;
    int own = hist[tid];
    int v = own;
    #pragma unroll
    for (int s = 1; s < 64; s <<= 1) {
        int u = __shfl_up(v, s, 64);
        if (lane >= s) v += u;
    }
    if (lane == 63) wsum[wv] = v;
    __syncthreads();
    int basew = 0;
    #pragma unroll
    for (int t = 0; t < NT / 64; ++t)
        if (t < wv) basew += wsum[t];
    int incl = basew + v;
    int sstart = incl - own;
    segstart[tid] = sstart;
    cursor[tid] = sstart;
    if (tid == NT - 1) tot_s = incl;
    // one global atomicAdd per active bin to reserve record space
    gbase[tid] = (tid < tpb && own > 0)
               ? atomicAdd(&counters[(b_idx * tpb + tid) * CSTRIDE], own) : 0;
    __syncthreads();

    // ---- phase B: scatter records into LDS staging ----
    #pragma unroll
    for (int k = 0; k < KPT; ++k) {
        unsigned int word = words[k];
        if (word == 0xFFFFFFFFu) continue;
        int ty = (int)(word >> 13);
        unsigned int cib = word & 8191u;
        int i = off + k * NT + tid;
        int slot = atomicAdd(&cursor[ty], 1);               // < CHUNK always
        staging[slot] = (cib << 19) | (unsigned)i;
    }
    __syncthreads();

    // ---- phase C: dense cooperative flush (all 256 lanes active) ----
    const int tot = tot_s;
    for (int j = tid; j < tot; j += NT) {
        // binary search: largest t with segstart[t] <= j
        int lo = 0, hi = THIST - 1;
        while (lo < hi) {
            int mid = (lo + hi + 1) >> 1;
            if (segstart[mid] <= j) lo = mid; else hi = mid - 1;
        }
        int t = lo;
        int gpos = gbase[t] + (j - segstart[t]);
        if (gpos < cap)                                      // drop-guard
            records[(size_t)(b_idx * tpb + t) * cap + gpos] = staging[j];
    }
}

// ---------------------------------------------------------------------------
// K2: per-bin LDS z-buffer replay + 2x2 argmax-by-conf pool + vflip + outputs.
// Fine bins (rpt=4 @ h=480), 24 KB LDS, init only cpt cells.
// ---------------------------------------------------------------------------
__global__ void __launch_bounds__(NT)
pool_bins_kernel(const float* __restrict__ alpha,   // [b,1,h,w]
                 const float* __restrict__ conf,    // [b,n]
                 const int* __restrict__ counters,
                 const unsigned int* __restrict__ records,
                 const int* __restrict__ d_h,
                 const int* __restrict__ d_w,
                 float* __restrict__ out_match,     // [b,h,w]
                 float* __restrict__ out_midx,      // [b,h,w]
                 int b, int n, int hw, int cap) {
    __shared__ int cells[CELLSZ];
    const int h = *d_h, w = *d_w;
    int H2, W2, rpt, cpt, tpb; bool geom_ok;
    derive_geom(h, w, n, H2, W2, rpt, cpt, tpb, geom_ok);
    if (!geom_ok) return;

    // XCD-affinity remap
    const int b_idx = blockIdx.x % b;
    const int ty    = blockIdx.x / b;
    if (ty >= tpb) return;
    const int bin = b_idx * tpb + ty;

    for (int i = threadIdx.x; i < cpt; i += NT) cells[i] = -1;
    __syncthreads();

    int cnt = counters[bin * CSTRIDE];
    if (cnt > cap) cnt = cap;
    const unsigned int* rec = records + (size_t)bin * cap;
    for (int r = threadIdx.x; r < cnt; r += NT) {
        unsigned int rr = rec[r];
        atomicMax(&cells[rr >> 19], (int)(rr & 0x7FFFFu));   // winner = max idx
    }
    __syncthreads();

    const int row0 = ty * rpt;
    int rmax = H2 - row0; if (rmax > rpt) rmax = rpt;         // even
    const float* A = alpha + (size_t)b_idx * hw;
    const float* C = conf + (size_t)b_idx * n;

    for (int q = 0; q < rmax / 2; ++q) {
        int hr = (row0 >> 1) + q;
        int r_out = h - 1 - hr;                               // vertical flip
        for (int c = threadIdx.x; c < w; c += NT) {
            // alpha gate uniform across the 2x2 window: = alpha[r_out][c]
            float av = A[r_out * w + c];
            float best = 0.0f;
            int besti = -1;
            if (av > 0.0f) {
                #pragma unroll
                for (int a = 0; a < 4; ++a) {
                    int dy = a >> 1, dx = a & 1;
                    int widx = cells[(2 * q + dy) * W2 + 2 * c + dx];
                    if (widx >= 0) {
                        float cv = C[widx];                   // always > 0
                        if (cv > best) { best = cv; besti = widx; }
                    }
                }
            }
            int o = b_idx * hw + r_out * w + c;
            out_match[o] = (best > 0.0f) ? 1.0f : 0.0f;
            out_midx[o]  = (float)besti;
        }
    }
}

extern "C" void kernel_launch(void* const* d_in, const int* in_sizes, int n_in,
                              void* d_out, int out_size, void* d_ws, size_t ws_size,
                              hipStream_t stream) {
    const float* alpha = (const float*)d_in[0];
    const float* beta  = (const float*)d_in[1];
    const float* pp    = (const float*)d_in[2];
    const float* conf  = (const float*)d_in[3];
    const float* pose  = (const float*)d_in[4];
    const float* Kmat  = (const float*)d_in[5];
    const int*   d_h   = (const int*)d_in[6];
    const int*   d_w   = (const int*)d_in[7];

    const int b  = in_sizes[4] / 16;     // pose [b,4,4]
    const int n  = in_sizes[3] / b;      // conf [b,n]
    const int hw = in_sizes[0] / b;      // alpha [b,1,h,w]

    float* out_match = (float*)d_out;
    float* out_midx  = out_match + (size_t)b * hw;
    float* out_conf  = out_midx + (size_t)b * hw;

    // tpb <= THIST always, so b*THIST bounds total bins.
    const int nb_ub = b * THIST;

    // Workspace layout: [counters | records]
    long avail_ints = (long)(ws_size / 4) - (long)nb_ub * CSTRIDE;
    long cap_l = avail_ints / (nb_ub > 0 ? nb_ub : 1);
    int cap = (int)cap_l;
    if (cap > 4096) cap = 4096;
    if (cap < 64) cap = 64;

    int* counters = (int*)d_ws;
    unsigned int* records = (unsigned int*)(counters + (size_t)nb_ub * CSTRIDE);

    // counters init via memset (graph-capturable)
    hipMemsetAsync(counters, 0, (size_t)nb_ub * CSTRIDE * sizeof(int), stream);

    const int bpb = (n + CHUNK - 1) / CHUNK;   // blocks per batch
    project_bin_kernel<<<b * bpb, NT, 0, stream>>>(
        pp, conf, pose, Kmat, beta, d_h, d_w,
        counters, records, out_conf, n, b, cap);

    pool_bins_kernel<<<nb_ub, NT, 0, stream>>>(
        alpha, conf, counters, records, d_h, d_w,
        out_match, out_midx, b, n, hw, cap);
}